// Round 7
// baseline (2739.519 us; speedup 1.0000x reference)
//
#include <hip/hip_runtime.h>
#include <math.h>

// ---------------- constants ----------------
#define SEQ 128
#define BATCH 256
#define INPUT 300
#define HIDDEN 1024
#define NG 4096              // 4*HIDDEN, gate-interleaved: n' = 4*j + gate
#define KH 1024
#define KXP 320              // x K padded 300->320
#define KT 1344              // KH + KXP
#define NKT 42               // KT/32 k-tiles
#define KTH 32               // KH/32 h k-tiles
#define NKTH 32              // head k-tiles (K=1024)
#define LINEARN 1024

typedef __attribute__((ext_vector_type(8))) short short8;
typedef __attribute__((ext_vector_type(4))) float floatx4;

__device__ __forceinline__ float sigf(float x)     { return 1.f / (1.f + __expf(-x)); }
__device__ __forceinline__ float tanhfast(float x) { return 2.f / (1.f + __expf(-2.f * x)) - 1.f; }

__device__ __forceinline__ unsigned short bf16_rne(float f) {
  unsigned u = __float_as_uint(f);
  u += 0x7FFFu + ((u >> 16) & 1u);
  return (unsigned short)(u >> 16);
}
__device__ __forceinline__ float bf16f(unsigned short s) {
  return __uint_as_float(((unsigned)s) << 16);
}

__device__ __forceinline__ void mfma3(floatx4& acc, short8 ah, short8 al, short8 bh, short8 bl) {
  acc = __builtin_amdgcn_mfma_f32_16x16x32_bf16(ah, bh, acc, 0, 0, 0);
  acc = __builtin_amdgcn_mfma_f32_16x16x32_bf16(ah, bl, acc, 0, 0, 0);
  acc = __builtin_amdgcn_mfma_f32_16x16x32_bf16(al, bh, acc, 0, 0, 0);
}
// W kept at bf16 (hi only); A split hi/lo corrects the h/x quantization.
__device__ __forceinline__ void mfma2(floatx4& acc, short8 ah, short8 al, short8 bh) {
  acc = __builtin_amdgcn_mfma_f32_16x16x32_bf16(ah, bh, acc, 0, 0, 0);
  acc = __builtin_amdgcn_mfma_f32_16x16x32_bf16(al, bh, acc, 0, 0, 0);
}

// ---------------- zero ----------------
__global__ __launch_bounds__(256) void zero_ws(float4* p, int n4) {
  int i = blockIdx.x * 256 + threadIdx.x;
  if (i < n4) p[i] = make_float4(0.f, 0.f, 0.f, 0.f);
}

// ---------------- weight pack: gate-interleave + pad, bf16 hi, FRAGMENT-MAJOR ----------------
// Wf: [ntile16(256)][kt(42)][lane(64)][8]; lane -> n' = ntile*16 + (lane&15),
//     k = kt*32 + (lane>>4)*8 + e. A wave-load at lane*8 is one coalesced 1KB dwordx4.
__global__ __launch_bounds__(256) void pack_w(
    const float* __restrict__ W_ih, const float* __restrict__ W_hh,
    unsigned short* __restrict__ Wf)
{
  int id = blockIdx.x * 256 + threadIdx.x;
  if (id >= (NG / 16) * NKT * 512) return;
  int e    = id & 7;
  int lane = (id >> 3) & 63;
  int rest = id >> 9;            // ntile*NKT + kt
  int kt   = rest % NKT;
  int ntile = rest / NKT;
  int n = ntile * 16 + (lane & 15);
  int k = kt * 32 + (lane >> 4) * 8 + e;
  int j = n >> 2, g = n & 3;
  int srow = g * HIDDEN + j;
  float w = 0.f;
  if (k < KH) w = W_hh[(size_t)srow * HIDDEN + k];
  else if (k - KH < INPUT) w = W_ih[(size_t)srow * INPUT + (k - KH)];
  Wf[id] = bf16_rne(w);
}

__global__ __launch_bounds__(256) void pack_bias(
    const float* __restrict__ b_ih, const float* __restrict__ b_hh,
    float* __restrict__ biasp)
{
  int n = blockIdx.x * 256 + threadIdx.x;
  if (n >= NG) return;
  int j = n >> 2, g = n & 3;
  int s = g * HIDDEN + j;
  biasp[n] = b_ih[s] + b_hh[s];
}

// ---------------- pack all x timesteps to bf16 hi/lo, padded 300->320 ----------------
__global__ __launch_bounds__(256) void pack_x(
    const float* __restrict__ x, unsigned short* __restrict__ xph,
    unsigned short* __restrict__ xpl)
{
  int id = blockIdx.x * 256 + threadIdx.x;
  if (id >= SEQ * BATCH * KXP) return;
  int row = id / KXP;
  int k = id - row * KXP;
  float v = (k < INPUT) ? x[(size_t)row * INPUT + k] : 0.f;
  unsigned short hi = bf16_rne(v);
  xph[id] = hi;
  xpl[id] = bf16_rne(v - bf16f(hi));
}

// ---------------- pack W1 (head) hi/lo ----------------
__global__ __launch_bounds__(256) void pack_w1(
    const float* __restrict__ W1, unsigned short* __restrict__ W1ph,
    unsigned short* __restrict__ W1pl)
{
  int id = blockIdx.x * 256 + threadIdx.x;
  if (id >= LINEARN * HIDDEN) return;
  float w = W1[id];
  unsigned short hi = bf16_rne(w);
  W1ph[id] = hi;
  W1pl[id] = bf16_rne(w - bf16f(hi));
}

// ---------------- fused LSTM step ----------------
// 64x64 tiles, 256 blocks (1/CU), XCD-swizzled. A (h/x hi+lo) staged via LDS
// double-buffer; B (W) fragment-major, loaded direct to registers (depth-2).
// K-loop order: barrier FIRST, then prefetch-issue -> barrier drain sees loads
// aged one full iteration (fixes the vmcnt(0)-before-s_barrier stall).
__global__ __launch_bounds__(256) void lstm_step(
    const unsigned short* __restrict__ xp_hi,   // [256][320] this step
    const unsigned short* __restrict__ xp_lo,
    const unsigned short* __restrict__ h_hi_r,  // [256][1024]
    const unsigned short* __restrict__ h_lo_r,
    const unsigned short* __restrict__ Wf,      // frag-major [256][42][512]
    const float* __restrict__ biasp,            // [4096]
    float* __restrict__ cst,                    // [256][1024] fp32 cell state
    unsigned short* __restrict__ h_hi_w,
    unsigned short* __restrict__ h_lo_w)
{
  // 2 bufs x {Ah, Al} x 64 rows x 40 stride = 20.5 KB
  __shared__ short sb[2 * 2 * 2560];

  const int t    = threadIdx.x;
  const int lane = t & 63;
  const int wave = t >> 6;
  const int wm   = (wave >> 1) * 32;
  const int wn   = (wave & 1) * 32;
  const int col  = lane & 15;
  const int quad = lane >> 4;
  const int r    = t >> 2;              // staging row 0..63
  const int k8   = (t & 3) * 8;         // k offset {0,8,16,24} shorts
  const int id     = blockIdx.x;
  const int jtile  = (id & 7) * 8 + ((id >> 3) & 7);   // XCD-local j grouping
  const int mt_    = id >> 6;                          // 0..3
  const int m0   = mt_ * 64;
  const int n0   = jtile * 64;
  const int j0   = jtile * 16;
  const int nta  = jtile * 4 + (wn >> 4);              // wave's base 16-col ntile

#define LOAD_A(kt, AH, AL) do {                                              \
    if ((kt) < KTH) {                                                        \
      const int ka = (kt) * 32 + k8;                                         \
      AH = *(const uint4*)(h_hi_r + (size_t)(m0 + r) * KH + ka);             \
      AL = *(const uint4*)(h_lo_r + (size_t)(m0 + r) * KH + ka);             \
    } else {                                                                 \
      const int kx = ((kt) - KTH) * 32 + k8;                                 \
      AH = *(const uint4*)(xp_hi + (size_t)(m0 + r) * KXP + kx);             \
      AL = *(const uint4*)(xp_lo + (size_t)(m0 + r) * KXP + kx);             \
    }                                                                        \
  } while (0)

#define LOAD_B(kt, B) do {                                                   \
    const size_t bo = ((size_t)(nta * NKT + (kt)) << 9) + lane * 8;          \
    B[0] = *(const short8*)(Wf + bo);                                        \
    B[1] = *(const short8*)(Wf + bo + ((size_t)NKT << 9));                   \
  } while (0)

#define STORE_A(base, AH, AL) do {                                           \
    *(uint4*)((base) +        r * 40 + k8) = AH;                             \
    *(uint4*)((base) + 2560 + r * 40 + k8) = AL;                             \
  } while (0)

  floatx4 acc[2][2];
#pragma unroll
  for (int i = 0; i < 2; ++i)
#pragma unroll
    for (int jj = 0; jj < 2; ++jj)
      acc[i][jj] = (floatx4){0.f, 0.f, 0.f, 0.f};

  uint4 cAh, cAl, nAh, nAl, tAh, tAl;
  short8 bcur[2], bnext[2];
  LOAD_A(0, tAh, tAl);
  LOAD_A(1, cAh, cAl);
  LOAD_B(0, bcur);
  STORE_A(sb, tAh, tAl);

  for (int kt = 0; kt < NKT; ++kt) {
    __syncthreads();                       // publish buf[kt&1]; pending vmem aged 1 iter
    if (kt + 2 < NKT) LOAD_A(kt + 2, nAh, nAl);
    if (kt + 1 < NKT) LOAD_B(kt + 1, bnext);

    short* bufp = sb + (kt & 1) * 5120;
    short8 ah[2], al[2];
#pragma unroll
    for (int mt = 0; mt < 2; ++mt) {
      const int row = (wm + mt * 16 + col) * 40 + quad * 8;
      ah[mt] = *(const short8*)(bufp + row);
      al[mt] = *(const short8*)(bufp + 2560 + row);
    }
#pragma unroll
    for (int mt = 0; mt < 2; ++mt)
#pragma unroll
      for (int nt = 0; nt < 2; ++nt)
        mfma2(acc[mt][nt], ah[mt], al[mt], bcur[nt]);

    if (kt + 1 < NKT) STORE_A(sb + ((kt + 1) & 1) * 5120, cAh, cAl);
    cAh = nAh; cAl = nAl;
    bcur[0] = bnext[0]; bcur[1] = bnext[1];
  }
#undef LOAD_A
#undef LOAD_B
#undef STORE_A

  // ---- epilogue: gates -> LDS [n'][m], fused cell update ----
  __syncthreads();
  float* epi = (float*)sb;   // 64*65 floats = 16.6 KB <= 20.5 KB
#pragma unroll
  for (int mt = 0; mt < 2; ++mt)
#pragma unroll
    for (int nt = 0; nt < 2; ++nt) {
      const int nl = wn + nt * 16 + col;
      const float bb = biasp[n0 + nl];
#pragma unroll
      for (int reg = 0; reg < 4; ++reg) {
        const int ml = wm + mt * 16 + quad * 4 + reg;
        epi[nl * 65 + ml] = acc[mt][nt][reg] + bb;
      }
    }
  __syncthreads();

  const int mloc = t >> 2;
  const int jl4  = (t & 3) * 4;
  const int m    = m0 + mloc;
  const int j    = j0 + jl4;
  float4 cold = *(const float4*)(cst + (size_t)m * HIDDEN + j);
  float cn[4], hn[4];
#pragma unroll
  for (int jj = 0; jj < 4; ++jj) {
    const int nl = (jl4 + jj) * 4;
    const float gi = epi[(nl + 0) * 65 + mloc];
    const float gf = epi[(nl + 1) * 65 + mloc];
    const float gg = epi[(nl + 2) * 65 + mloc];
    const float go = epi[(nl + 3) * 65 + mloc];
    const float cc = (jj == 0) ? cold.x : (jj == 1) ? cold.y : (jj == 2) ? cold.z : cold.w;
    const float cnew = sigf(gf) * cc + sigf(gi) * tanhfast(gg);
    cn[jj] = cnew;
    hn[jj] = sigf(go) * tanhfast(cnew);
  }
  *(float4*)(cst + (size_t)m * HIDDEN + j) = make_float4(cn[0], cn[1], cn[2], cn[3]);
  ushort4 uh, ul;
  uh.x = bf16_rne(hn[0]); uh.y = bf16_rne(hn[1]); uh.z = bf16_rne(hn[2]); uh.w = bf16_rne(hn[3]);
  ul.x = bf16_rne(hn[0] - bf16f(uh.x));
  ul.y = bf16_rne(hn[1] - bf16f(uh.y));
  ul.z = bf16_rne(hn[2] - bf16f(uh.z));
  ul.w = bf16_rne(hn[3] - bf16f(uh.w));
  *(ushort4*)(h_hi_w + (size_t)m * HIDDEN + j) = uh;
  *(ushort4*)(h_lo_w + (size_t)m * HIDDEN + j) = ul;
}

// ---------------- head GEMM: z = h @ W1^T + b1 (64x64 LDS pipelined, 3-MFMA) ----------------
__global__ __launch_bounds__(256) void head_gemm(
    const unsigned short* __restrict__ Ah_,     // h_hi [256][1024]
    const unsigned short* __restrict__ Al_,
    const unsigned short* __restrict__ Bh_,     // W1 hi [1024][1024]
    const unsigned short* __restrict__ Bl_,
    const float* __restrict__ bias,
    float* __restrict__ C)                      // z [256][1024]
{
  __shared__ short sb[2 * 4 * 2560];

  const int t    = threadIdx.x;
  const int lane = t & 63;
  const int wave = t >> 6;
  const int wm   = (wave >> 1) * 32;
  const int wn   = (wave & 1) * 32;
  const int col  = lane & 15;
  const int quad = lane >> 4;
  const int r    = t >> 2;
  const int k8   = (t & 3) * 8;
  const int m0   = blockIdx.y * 64;
  const int n0   = blockIdx.x * 64;

#define LOAD_TILE(kt, AH, AL, BH, BL) do {                                   \
    const int ka = (kt) * 32 + k8;                                           \
    AH = *(const uint4*)(Ah_ + (size_t)(m0 + r) * KH + ka);                  \
    AL = *(const uint4*)(Al_ + (size_t)(m0 + r) * KH + ka);                  \
    BH = *(const uint4*)(Bh_ + (size_t)(n0 + r) * KH + ka);                  \
    BL = *(const uint4*)(Bl_ + (size_t)(n0 + r) * KH + ka);                  \
  } while (0)

#define STORE_TILE(base, AH, AL, BH, BL) do {                                \
    *(uint4*)((base) +        r * 40 + k8) = AH;                             \
    *(uint4*)((base) + 2560 + r * 40 + k8) = AL;                             \
    *(uint4*)((base) + 5120 + r * 40 + k8) = BH;                             \
    *(uint4*)((base) + 7680 + r * 40 + k8) = BL;                             \
  } while (0)

  floatx4 acc[2][2];
#pragma unroll
  for (int i = 0; i < 2; ++i)
#pragma unroll
    for (int jj = 0; jj < 2; ++jj)
      acc[i][jj] = (floatx4){0.f, 0.f, 0.f, 0.f};

  uint4 cAh, cAl, cBh, cBl, nAh, nAl, nBh, nBl, tAh, tAl, tBh, tBl;
  LOAD_TILE(0, tAh, tAl, tBh, tBl);
  LOAD_TILE(1, cAh, cAl, cBh, cBl);
  STORE_TILE(sb, tAh, tAl, tBh, tBl);

  for (int kt = 0; kt < NKTH; ++kt) {
    __syncthreads();
    if (kt + 2 < NKTH) LOAD_TILE(kt + 2, nAh, nAl, nBh, nBl);
    short* bufp = sb + (kt & 1) * 10240;

    short8 ah[2], al[2], bh[2], bl[2];
#pragma unroll
    for (int mt = 0; mt < 2; ++mt) {
      const int row = (wm + mt * 16 + col) * 40 + quad * 8;
      ah[mt] = *(const short8*)(bufp + row);
      al[mt] = *(const short8*)(bufp + 2560 + row);
    }
#pragma unroll
    for (int nt = 0; nt < 2; ++nt) {
      const int row = (wn + nt * 16 + col) * 40 + quad * 8;
      bh[nt] = *(const short8*)(bufp + 5120 + row);
      bl[nt] = *(const short8*)(bufp + 7680 + row);
    }
#pragma unroll
    for (int mt = 0; mt < 2; ++mt)
#pragma unroll
      for (int nt = 0; nt < 2; ++nt)
        mfma3(acc[mt][nt], ah[mt], al[mt], bh[nt], bl[nt]);

    if (kt + 1 < NKTH) STORE_TILE(sb + ((kt + 1) & 1) * 10240, cAh, cAl, cBh, cBl);
    cAh = nAh; cAl = nAl; cBh = nBh; cBl = nBl;
  }
#undef LOAD_TILE
#undef STORE_TILE

#pragma unroll
  for (int mt = 0; mt < 2; ++mt)
#pragma unroll
    for (int nt = 0; nt < 2; ++nt) {
      const int nl = n0 + wn + nt * 16 + col;
      const float bb = bias[nl];
#pragma unroll
      for (int reg = 0; reg < 4; ++reg) {
        const int ml = m0 + wm + mt * 16 + quad * 4 + reg;
        C[(size_t)ml * LINEARN + nl] = acc[mt][nt][reg] + bb;
      }
    }
}

// ---------------- BN stats ----------------
__global__ __launch_bounds__(64) void bn_stats(
    const float* __restrict__ z, float* __restrict__ mean, float* __restrict__ rstd)
{
  const int n = blockIdx.x;
  const int t = threadIdx.x;
  float s = 0.f, s2 = 0.f;
  for (int r = t; r < BATCH; r += 64) {
    const float v = z[(size_t)r * LINEARN + n];
    s += v; s2 += v * v;
  }
#pragma unroll
  for (int off = 32; off > 0; off >>= 1) {
    s  += __shfl_down(s,  off, 64);
    s2 += __shfl_down(s2, off, 64);
  }
  if (t == 0) {
    const float mm = s * (1.f / BATCH);
    mean[n] = mm;
    rstd[n] = rsqrtf(s2 * (1.f / BATCH) - mm * mm + 1e-5f);
  }
}

// ---------------- head out ----------------
__global__ __launch_bounds__(256) void head_out(
    const float* __restrict__ z, const float* __restrict__ mean, const float* __restrict__ rstd,
    const float* __restrict__ gamma, const float* __restrict__ beta,
    const float* __restrict__ W2, const float* __restrict__ b2, float* __restrict__ out)
{
  const int b = blockIdx.x;
  const int t = threadIdx.x;
  float acc = 0.f;
  for (int n = t; n < LINEARN; n += 256) {
    float v = (z[(size_t)b * LINEARN + n] - mean[n]) * rstd[n] * gamma[n] + beta[n];
    v = fmaxf(v, 0.f);
    acc += v * W2[n];
  }
#pragma unroll
  for (int off = 32; off > 0; off >>= 1) acc += __shfl_down(acc, off, 64);
  __shared__ float ls[4];
  if ((t & 63) == 0) ls[t >> 6] = acc;
  __syncthreads();
  if (t == 0) {
    const float tot = ls[0] + ls[1] + ls[2] + ls[3] + b2[0];
    out[b] = 3.f / (1.f + __expf(-tot));
  }
}

// ---------------- launch ----------------
extern "C" void kernel_launch(void* const* d_in, const int* in_sizes, int n_in,
                              void* d_out, int out_size, void* d_ws, size_t ws_size,
                              hipStream_t stream) {
  const float* x     = (const float*)d_in[0];
  const float* W_ih  = (const float*)d_in[1];
  const float* W_hh  = (const float*)d_in[2];
  const float* b_ih  = (const float*)d_in[3];
  const float* b_hh  = (const float*)d_in[4];
  const float* W1    = (const float*)d_in[5];
  const float* b1    = (const float*)d_in[6];
  const float* gamma = (const float*)d_in[7];
  const float* beta  = (const float*)d_in[8];
  const float* W2    = (const float*)d_in[9];
  const float* b2    = (const float*)d_in[10];
  float* out = (float*)d_out;

  char* w = (char*)d_ws;
  // zero region (contiguous 2 MB): h_hi0, h_lo0, c
  unsigned short* h_hi0 = (unsigned short*)(w + 0);          // 512 KB
  unsigned short* h_lo0 = (unsigned short*)(w + 524288);     // 512 KB
  float*          cst   = (float*)(w + 1048576);             // 1 MB
  unsigned short* h_hi1 = (unsigned short*)(w + 2097152);
  unsigned short* h_lo1 = (unsigned short*)(w + 2621440);
  unsigned short* Wf    = (unsigned short*)(w + 3145728);    // 11,010,048 B
  float*          biasp = (float*)(w + 14155776);            // 16 KB
  unsigned short* xph   = (unsigned short*)(w + 14172160);   // 20,971,520 B
  unsigned short* xpl   = (unsigned short*)(w + 35143680);   // 20,971,520 B
  unsigned short* W1ph  = (unsigned short*)(w + 56115200);   // 2 MB
  unsigned short* W1pl  = (unsigned short*)(w + 58212352);   // 2 MB
  float*          z     = (float*)(w + 60309504);            // 1 MB
  float*          mean  = (float*)(w + 61358080);
  float*          rstd  = (float*)(w + 61362176);

  zero_ws<<<512, 256, 0, stream>>>((float4*)w, 131072);
  pack_w<<<((NG / 16) * NKT * 512 + 255) / 256, 256, 0, stream>>>(W_ih, W_hh, Wf);
  pack_bias<<<NG / 256, 256, 0, stream>>>(b_ih, b_hh, biasp);
  pack_x<<<(SEQ * BATCH * KXP + 255) / 256, 256, 0, stream>>>(x, xph, xpl);
  pack_w1<<<(LINEARN * HIDDEN + 255) / 256, 256, 0, stream>>>(W1, W1ph, W1pl);

  for (int t = 0; t < SEQ; ++t) {
    const unsigned short* hr_hi = (t & 1) ? h_hi1 : h_hi0;
    const unsigned short* hr_lo = (t & 1) ? h_lo1 : h_lo0;
    unsigned short* hw_hi = (t & 1) ? h_hi0 : h_hi1;
    unsigned short* hw_lo = (t & 1) ? h_lo0 : h_lo1;
    lstm_step<<<256, 256, 0, stream>>>(
        xph + (size_t)t * BATCH * KXP, xpl + (size_t)t * BATCH * KXP,
        hr_hi, hr_lo, Wf, biasp, cst, hw_hi, hw_lo);
  }

  // final h (t=127 odd) is in h_hi0/h_lo0
  head_gemm<<<dim3(LINEARN / 64, BATCH / 64), 256, 0, stream>>>(
      h_hi0, h_lo0, W1ph, W1pl, b1, z);
  bn_stats<<<LINEARN, 64, 0, stream>>>(z, mean, rstd);
  head_out<<<BATCH, 256, 0, stream>>>(z, mean, rstd, gamma, beta, W2, b2, out);
}